// Round 14
// baseline (138.613 us; speedup 1.0000x reference)
//
#include <hip/hip_runtime.h>
#include <hip/hip_bf16.h>
#include <stdint.h>

typedef unsigned short u16;
typedef __attribute__((ext_vector_type(8))) __bf16 bf16x8;
typedef __attribute__((ext_vector_type(4))) float f32x4;
typedef __attribute__((ext_vector_type(16))) float f32x16;
typedef __attribute__((ext_vector_type(8))) u16 u16x8;

__device__ __forceinline__ u16 f2bf(float f) {
  union { float f; unsigned int u; } v; v.f = f;
  unsigned int r = v.u + 0x7fffu + ((v.u >> 16) & 1u);
  return (u16)(r >> 16);
}
__device__ __forceinline__ unsigned pack2(float lo, float hi) {
  return (unsigned)f2bf(lo) | ((unsigned)f2bf(hi) << 16);
}

__device__ __forceinline__ f32x4 mfma16(bf16x8 a, bf16x8 b, f32x4 c) {
  return __builtin_amdgcn_mfma_f32_16x16x32_bf16(a, b, c, 0, 0, 0);
}
__device__ __forceinline__ f32x16 mfma32(bf16x8 a, bf16x8 b, f32x16 c) {
  return __builtin_amdgcn_mfma_f32_32x32x16_bf16(a, b, c, 0, 0, 0);
}

__device__ __forceinline__ void gload16(const void* g, void* l) {
  __builtin_amdgcn_global_load_lds((const __attribute__((address_space(1))) void*)g,
                                   (__attribute__((address_space(3))) void*)l,
                                   16, 0, 0);
}

// ---------------- elementwise cast fp32 -> bf16 ----------------
__global__ void cast_bf16_kernel(const float* __restrict__ in, u16* __restrict__ out, int n) {
  int i = (blockIdx.x * 256 + threadIdx.x) * 8;
  if (i >= n) return;
  const float4* p = (const float4*)(in + i);
  float4 a = p[0], b = p[1];
  u16x8 o;
  o[0] = f2bf(a.x); o[1] = f2bf(a.y); o[2] = f2bf(a.z); o[3] = f2bf(a.w);
  o[4] = f2bf(b.x); o[5] = f2bf(b.y); o[6] = f2bf(b.z); o[7] = f2bf(b.w);
  *(u16x8*)(out + i) = o;
}

// ---------------- transpose + cast: in[R][C] fp32 -> out[C][R] bf16 ----------------
__global__ void transpose_cast_k(const float* __restrict__ in, u16* __restrict__ out,
                                 int R, int Ccols) {
  __shared__ float tile[64][65];
  const int c0 = (int)blockIdx.x << 6, r0 = (int)blockIdx.y << 6;
  const int tx = threadIdx.x & 63, ty = threadIdx.x >> 6;
#pragma unroll
  for (int i = ty; i < 64; i += 4)
    tile[i][tx] = in[(size_t)(r0 + i) * Ccols + c0 + tx];
  __syncthreads();
#pragma unroll
  for (int i = ty; i < 64; i += 4)
    out[(size_t)(c0 + i) * R + r0 + tx] = f2bf(tile[tx][i]);
}

// ---------------- QKV GEMM, BK=64, fused bias+RoPE+head-split epilogue ----------------
__global__ __launch_bounds__(256, 3)
void gemm_qkv(const u16* __restrict__ A, const u16* __restrict__ Bt,
              const float* __restrict__ bias,
              const float* __restrict__ fc, const float* __restrict__ fs,
              u16* __restrict__ qr, u16* __restrict__ kr, u16* __restrict__ vr) {
  const int K = 1024;
  __shared__ __align__(16) u16 smem[128 * 136];   // 34.8 KB; As/Bs alias front 32 KB
  u16* const As = smem;           // [2][128][32]
  u16* const Bs = smem + 8192;    // [2][128][32]
  const int m0 = (int)(blockIdx.x / 24) << 7;
  const int n0 = (int)(blockIdx.x % 24) << 7;
  const int tid = threadIdx.x;
  const int l = tid & 63, lg = l >> 4, ll = l & 15;
  const int w = tid >> 6;
  const int wr = (w >> 1) << 6, wc = (w & 1) << 6;
  const int srow = tid >> 2, scol = (tid & 3) << 3;
  const u16* ga = A + (size_t)(m0 + srow) * K + scol;
  const u16* gb = Bt + (size_t)(n0 + srow) * K + scol;
  const size_t K64 = (size_t)64 * K;
  u16* const la00 = &As[srow * 32 + scol];
  u16* const la01 = &As[4096 + srow * 32 + scol];
  u16* const la10 = &As[(srow + 64) * 32 + scol];
  u16* const la11 = &As[4096 + (srow + 64) * 32 + scol];
  u16* const lb00 = &Bs[srow * 32 + scol];
  u16* const lb01 = &Bs[4096 + srow * 32 + scol];
  u16* const lb10 = &Bs[(srow + 64) * 32 + scol];
  u16* const lb11 = &Bs[4096 + (srow + 64) * 32 + scol];
  f32x4 acc[4][4] = {};
  for (int kt = 0; kt < K; kt += 64) {
    gload16(ga + kt, la00);       gload16(ga + kt + 32, la01);
    gload16(ga + kt + K64, la10); gload16(ga + kt + K64 + 32, la11);
    gload16(gb + kt, lb00);       gload16(gb + kt + 32, lb01);
    gload16(gb + kt + K64, lb10); gload16(gb + kt + K64 + 32, lb11);
    __syncthreads();
#pragma unroll
    for (int h = 0; h < 2; ++h) {
      bf16x8 a[4], b[4];
#pragma unroll
      for (int i = 0; i < 4; ++i) {
        a[i] = *(const bf16x8*)&As[h * 4096 + (wr + i * 16 + ll) * 32 + lg * 8];
        b[i] = *(const bf16x8*)&Bs[h * 4096 + (wc + i * 16 + ll) * 32 + lg * 8];
      }
#pragma unroll
      for (int mi = 0; mi < 4; ++mi)
#pragma unroll
        for (int ni = 0; ni < 4; ++ni)
          acc[mi][ni] = mfma16(a[mi], b[ni], acc[mi][ni]);
    }
    __syncthreads();
  }
  // ---- stage 1: bias + rope -> LDS tile [128][136] ----
  const int sec = n0 >> 10;                       // 0=Q, 1=K, 2=V
  u16* const dst = (sec == 0) ? qr : (sec == 1) ? kr : vr;
  const int h0 = (n0 & 1023) >> 6;
#pragma unroll
  for (int ni = 0; ni < 4; ++ni) {
    const int cc = wc + ni * 16 + ll;
    const int n = n0 + cc;
    const int d = n & 63;
    const float bi_ = bias[n];
    const int i2 = d >> 1;
    const bool odd = d & 1;
#pragma unroll
    for (int mi = 0; mi < 4; ++mi) {
#pragma unroll
      for (int r = 0; r < 4; ++r) {
        const int rr = wr + mi * 16 + lg * 4 + r;
        const int s = (m0 + rr) & 2047;
        float v = acc[mi][ni][r] + bi_;
        if (sec < 2) {
          const float c = fc[s * 32 + i2], sn = fs[s * 32 + i2];
          const float p = __shfl_xor(v, 1);
          v = odd ? (p * sn + v * c) : (v * c - p * sn);
          if (sec == 0) v *= 0.125f;
        }
        smem[rr * 136 + cc] = f2bf(v);
      }
    }
  }
  __syncthreads();
  // ---- stage 2: coalesced uint4 stores ----
#pragma unroll
  for (int it = 0; it < 8; ++it) {
    const int c = it * 256 + tid;
    const int j = c & 7, hh = (c >> 3) & 1, rr = c >> 4;
    const int row = m0 + rr;
    const int bb = row >> 11, ss = row & 2047;
    const uint4 val = *(const uint4*)&smem[rr * 136 + hh * 64 + j * 8];
    *(uint4*)&dst[((size_t)(((bb << 4) + h0 + hh) << 11) + ss) * 64 + j * 8] = val;
  }
}

// ---------------- GEMM (O-proj): BK=64, fp32 out ----------------
__global__ __launch_bounds__(256, 2)
void gemm_bt(const u16* __restrict__ A, const u16* __restrict__ Bt,
             const float* __restrict__ bias, float* __restrict__ C,
             int M, int N, int K) {
  __shared__ __align__(16) u16 As[2 * 128 * 32];
  __shared__ __align__(16) u16 Bs[2 * 128 * 32];
  const int nb = N >> 7;
  const int m0 = (int)(blockIdx.x / nb) << 7;
  const int n0 = (int)(blockIdx.x % nb) << 7;
  const int tid = threadIdx.x;
  const int l = tid & 63, lg = l >> 4, ll = l & 15;
  const int w = tid >> 6;
  const int wr = (w >> 1) << 6, wc = (w & 1) << 6;
  const int srow = tid >> 2, scol = (tid & 3) << 3;
  const u16* ga = A + (size_t)(m0 + srow) * K + scol;
  const u16* gb = Bt + (size_t)(n0 + srow) * K + scol;
  const size_t K64 = (size_t)64 * K;
  u16* const la00 = &As[srow * 32 + scol];
  u16* const la01 = &As[4096 + srow * 32 + scol];
  u16* const la10 = &As[(srow + 64) * 32 + scol];
  u16* const la11 = &As[4096 + (srow + 64) * 32 + scol];
  u16* const lb00 = &Bs[srow * 32 + scol];
  u16* const lb01 = &Bs[4096 + srow * 32 + scol];
  u16* const lb10 = &Bs[(srow + 64) * 32 + scol];
  u16* const lb11 = &Bs[4096 + (srow + 64) * 32 + scol];
  f32x4 acc[4][4] = {};
  for (int kt = 0; kt < K; kt += 64) {
    gload16(ga + kt, la00);       gload16(ga + kt + 32, la01);
    gload16(ga + kt + K64, la10); gload16(ga + kt + K64 + 32, la11);
    gload16(gb + kt, lb00);       gload16(gb + kt + 32, lb01);
    gload16(gb + kt + K64, lb10); gload16(gb + kt + K64 + 32, lb11);
    __syncthreads();
#pragma unroll
    for (int h = 0; h < 2; ++h) {
      bf16x8 a[4], b[4];
#pragma unroll
      for (int i = 0; i < 4; ++i) {
        a[i] = *(const bf16x8*)&As[h * 4096 + (wr + i * 16 + ll) * 32 + lg * 8];
        b[i] = *(const bf16x8*)&Bs[h * 4096 + (wc + i * 16 + ll) * 32 + lg * 8];
      }
#pragma unroll
      for (int mi = 0; mi < 4; ++mi)
#pragma unroll
        for (int ni = 0; ni < 4; ++ni)
          acc[mi][ni] = mfma16(a[mi], b[ni], acc[mi][ni]);
    }
    __syncthreads();
  }
#pragma unroll
  for (int mi = 0; mi < 4; ++mi) {
#pragma unroll
    for (int r = 0; r < 4; ++r) {
      const int row = m0 + wr + mi * 16 + lg * 4 + r;
      float* crow = C + (size_t)row * N + n0 + wc;
#pragma unroll
      for (int ni = 0; ni < 4; ++ni)
        crow[ni * 16 + ll] = acc[mi][ni][r] + bias[n0 + wc + ni * 16 + ll];
    }
  }
}

// ---------------- V: vr[bh][s][d] bf16 -> vtc[bh][chunk64][64 d][64 kv] (chunked V^T) ----------------
__global__ void v_transpose_bf16(const u16* __restrict__ vr, u16* __restrict__ vtc) {
  __shared__ u16 tile[64][66];
  const int bh = blockIdx.x;
  const int s0 = (int)blockIdx.y << 6;
  const int tx = threadIdx.x & 63, ty = threadIdx.x >> 6;
#pragma unroll
  for (int i = ty; i < 64; i += 4)
    tile[i][tx] = vr[((size_t)bh * 2048 + s0 + i) * 64 + tx];
  __syncthreads();
  u16* const outc = vtc + ((size_t)bh * 32 + (s0 >> 6)) * 4096;
#pragma unroll
  for (int i = ty; i < 64; i += 4)
    outc[i * 64 + tx] = tile[tx][i];
}

// ---------------- flash attention v10: KV-split (flash-decoding style) ----------------
// Compute loop = v5.1 VERBATIM (best known). Work decomposition changed:
// q-tiles 8..15 (the heavy half) are split into TWO KV segments of exactly
// qt+1 <= 16 chunks each; light tiles (qt 0..7) unsplit. Every segment is
// <=16 chunks -> the single-block serial chain that set the old makespan
// (32 chunks) is halved. Split segments emit unnormalized fp32 partials +
// (m,l); attn_merge reconciles. Grid 768 (3/CU), heavy segments first.
__global__ __launch_bounds__(256, 2)
void attn_k(const u16* __restrict__ qr, const u16* __restrict__ kr,
            const u16* __restrict__ vtc, u16* __restrict__ aout,
            float* __restrict__ pO, float* __restrict__ pML) {
  __shared__ __align__(16) char kvlds[16384];     // [0:8K) K tile, [8K:16K) V^T tile
  const int bi = (int)blockIdx.x;
  const int bh = bi & 31;
  const int sidx = bi >> 5;                       // 0..23
  int qt, ch0, ch1, half;
  bool split;
  if (sidx < 16) {                                // split segments (heavy tiles)
    qt = 15 - (sidx >> 1);
    half = sidx & 1;
    split = true;
    const int hc = qt + 1;                        // nch = 2qt+2 -> two equal halves
    ch0 = half ? hc : 0;
    ch1 = half ? (2 * qt + 2) : hc;
  } else {                                        // light tiles, unsplit
    qt = 23 - sidx;                               // 7..0
    half = 0;
    split = false;
    ch0 = 0;
    ch1 = 2 * qt + 2;
  }
  const int tid = threadIdx.x;
  const int w = tid >> 6, l = tid & 63, hi = l >> 5, ql = l & 31;
  const u16* Q  = qr + (size_t)bh * (2048 * 64);
  const u16* Kp = kr + (size_t)bh * (2048 * 64);
  const int q0w = (qt << 7) + (w << 5);
  const int qg = q0w + ql;
  bf16x8 qf[4];
#pragma unroll
  for (int mi = 0; mi < 4; ++mi)
    qf[mi] = *(const bf16x8*)&Q[(size_t)qg * 64 + mi * 16 + hi * 8];
  const int sr = tid >> 2, sc = (tid & 3) * 32;
  const int wo0 = (sr * 128 + sc) ^ ((sr & 7) << 4);
  const int wo1 = (sr * 128 + sc + 16) ^ ((sr & 7) << 4);
  const char* kga = (const char*)(Kp + (size_t)sr * 64) + sc;                    // + ch*8192
  const char* vga = (const char*)(vtc + (size_t)bh * 32 * 4096) + sr * 128 + sc; // + ch*8192
  const int swz = (ql & 7) << 4;
  f32x16 oa = {}, ob = {};
  float mrow = -1e30f, lp = 0.f;
  uint4 sk0 = *(const uint4*)(kga + (size_t)ch0 * 8192);
  uint4 sk1 = *(const uint4*)(kga + (size_t)ch0 * 8192 + 16);
  uint4 sv0 = *(const uint4*)(vga + (size_t)ch0 * 8192);
  uint4 sv1 = *(const uint4*)(vga + (size_t)ch0 * 8192 + 16);
  for (int ch = ch0; ch < ch1; ++ch) {
    asm volatile("s_waitcnt vmcnt(0)" ::: "memory");
    asm volatile("s_barrier" ::: "memory");
    *(uint4*)(kvlds + wo0) = sk0;
    *(uint4*)(kvlds + wo1) = sk1;
    *(uint4*)(kvlds + 8192 + wo0) = sv0;
    *(uint4*)(kvlds + 8192 + wo1) = sv1;
    if (ch + 1 < ch1) {
      const size_t kof = (size_t)(ch + 1) * 8192;
      sk0 = *(const uint4*)(kga + kof); sk1 = *(const uint4*)(kga + kof + 16);
      sv0 = *(const uint4*)(vga + kof); sv1 = *(const uint4*)(vga + kof + 16);
    }
    asm volatile("s_waitcnt lgkmcnt(0)" ::: "memory");
    asm volatile("s_barrier" ::: "memory");
    const int kb = ch << 6;
    if (kb > q0w + 31) continue;
    f32x16 s0 = {}, s1 = {};
#pragma unroll
    for (int mi = 0; mi < 4; ++mi) {
      const int cb = mi * 32 + hi * 16;
      const bf16x8 k0 = *(const bf16x8*)(kvlds + ((ql * 128 + cb) ^ swz));
      const bf16x8 k1 = *(const bf16x8*)(kvlds + (((32 + ql) * 128 + cb) ^ swz));
      s0 = mfma32(k0, qf[mi], s0);
      s1 = mfma32(k1, qf[mi], s1);
    }
    if (kb + 63 > q0w) {
#pragma unroll
      for (int r = 0; r < 16; ++r) {
        const int kvo = (r & 3) + 8 * (r >> 2) + 4 * hi;
        if (kb + kvo > qg) s0[r] = -1e30f;
        if (kb + 32 + kvo > qg) s1[r] = -1e30f;
      }
    }
    float mx = s0[0];
#pragma unroll
    for (int r = 1; r < 16; ++r) mx = fmaxf(mx, s0[r]);
#pragma unroll
    for (int r = 0; r < 16; ++r) mx = fmaxf(mx, s1[r]);
    mx = fmaxf(mx, __shfl_xor(mx, 32));
    if (!__all(mx <= mrow + 8.f)) {
      const float mn = fmaxf(mrow, mx);
      const float esc = __expf(mrow - mn);
      mrow = mn;
      lp *= esc;
#pragma unroll
      for (int r = 0; r < 16; ++r) { oa[r] *= esc; ob[r] *= esc; }
    }
    float p0[16], p1[16];
#pragma unroll
    for (int r = 0; r < 16; ++r) {
      p0[r] = __expf(s0[r] - mrow);
      p1[r] = __expf(s1[r] - mrow);
      lp += p0[r] + p1[r];
    }
    bf16x8 pb[4];
#pragma unroll
    for (int s = 0; s < 2; ++s) {
      const float* ps = s ? p1 : p0;
#pragma unroll
      for (int j = 0; j < 2; ++j) {
        const unsigned X0 = pack2(ps[j * 8 + 0], ps[j * 8 + 1]);
        const unsigned X1 = pack2(ps[j * 8 + 2], ps[j * 8 + 3]);
        const unsigned Y0 = pack2(ps[j * 8 + 4], ps[j * 8 + 5]);
        const unsigned Y1 = pack2(ps[j * 8 + 6], ps[j * 8 + 7]);
        const unsigned sX0 = (unsigned)__shfl_xor((int)X0, 32);
        const unsigned sX1 = (unsigned)__shfl_xor((int)X1, 32);
        const unsigned sY0 = (unsigned)__shfl_xor((int)Y0, 32);
        const unsigned sY1 = (unsigned)__shfl_xor((int)Y1, 32);
        union { unsigned u[4]; bf16x8 v; } t;
        t.u[0] = hi ? sY0 : X0;
        t.u[1] = hi ? sY1 : X1;
        t.u[2] = hi ? Y0 : sX0;
        t.u[3] = hi ? Y1 : sX1;
        pb[s * 2 + j] = t.v;
      }
    }
#pragma unroll
    for (int jj = 0; jj < 4; ++jj) {
      const int cb = jj * 32 + hi * 16;
      const bf16x8 va = *(const bf16x8*)(kvlds + 8192 + ((ql * 128 + cb) ^ swz));
      const bf16x8 vb = *(const bf16x8*)(kvlds + 8192 + (((32 + ql) * 128 + cb) ^ swz));
      oa = mfma32(va, pb[jj], oa);
      ob = mfma32(vb, pb[jj], ob);
    }
  }
  lp += __shfl_xor(lp, 32);
  if (!split) {
    const float inv = 1.0f / lp;
    const int hcol = (bh & 15) << 6;
    const int tok = ((bh >> 4) << 11) + qg;
    unsigned* orow = (unsigned*)(aout + (size_t)tok * 1024 + hcol);
#pragma unroll
    for (int r = 0; r < 16; r += 2) {
      const int d0 = (r & 3) + 8 * (r >> 2) + 4 * hi;
      orow[d0 >> 1]        = pack2(oa[r] * inv, oa[r + 1] * inv);
      orow[(32 + d0) >> 1] = pack2(ob[r] * inv, ob[r + 1] * inv);
    }
  } else {
    // unnormalized partials + (m, l); rows 1024..2047 of this bh
    const int ridx = (bh << 10) + (qg - 1024);
    float* prow = pO + ((size_t)ridx * 2 + half) * 64;
#pragma unroll
    for (int r = 0; r < 16; r += 2) {
      const int d0 = (r & 3) + 8 * (r >> 2) + 4 * hi;
      *(float2*)&prow[d0]      = make_float2(oa[r], oa[r + 1]);
      *(float2*)&prow[32 + d0] = make_float2(ob[r], ob[r + 1]);
    }
    if (hi == 0) {
      pML[((size_t)ridx * 2 + half) * 2 + 0] = mrow;
      pML[((size_t)ridx * 2 + half) * 2 + 1] = lp;
    }
  }
}

// ---------------- merge the two KV-split partials ----------------
__global__ void attn_merge(const float* __restrict__ pO, const float* __restrict__ pML,
                           u16* __restrict__ aout) {
  const int idx = (int)blockIdx.x * 256 + threadIdx.x;  // 32*1024*64 lanes
  const int d = idx & 63;
  const int rr = idx >> 6;                              // bh*1024 + (row-1024)
  const float mA = pML[rr * 4 + 0], lA = pML[rr * 4 + 1];
  const float mB = pML[rr * 4 + 2], lB = pML[rr * 4 + 3];
  const float M = fmaxf(mA, mB);
  const float eA = __expf(mA - M), eB = __expf(mB - M);
  const float num = pO[((size_t)rr * 2 + 0) * 64 + d] * eA
                  + pO[((size_t)rr * 2 + 1) * 64 + d] * eB;
  const float den = lA * eA + lB * eB;
  const int bh = rr >> 10, row = (rr & 1023) + 1024;
  const int tok = ((bh >> 4) << 11) + row;
  const int hcol = (bh & 15) << 6;
  aout[(size_t)tok * 1024 + hcol + d] = f2bf(num / den);
}

extern "C" void kernel_launch(void* const* d_in, const int* in_sizes, int n_in,
                              void* d_out, int out_size, void* d_ws, size_t ws_size,
                              hipStream_t stream) {
  const float* x    = (const float*)d_in[0];
  const float* fc   = (const float*)d_in[2];
  const float* fs   = (const float*)d_in[3];
  const float* Wqkv = (const float*)d_in[4];
  const float* bqkv = (const float*)d_in[5];
  const float* Wo   = (const float*)d_in[6];
  const float* bo   = (const float*)d_in[7];
  float* out = (float*)d_out;

  size_t off = 0;
  auto alloc = [&](size_t bytes) {
    void* p = (char*)d_ws + off;
    off += (bytes + 255) & ~(size_t)255;
    return p;
  };
  u16*   xb   = (u16*)  alloc(4096ull * 1024 * 2);   // x bf16
  u16*   wqt  = (u16*)  alloc(3072ull * 1024 * 2);   // W_qkv^T bf16
  u16*   wot  = (u16*)  alloc(1024ull * 1024 * 2);   // W_o^T bf16
  u16*   qr_  = (u16*)  alloc(32ull * 2048 * 64 * 2);// q roped, head-major
  u16*   kr_  = (u16*)  alloc(32ull * 2048 * 64 * 2);// k roped, head-major
  u16*   vr_  = (u16*)  alloc(32ull * 2048 * 64 * 2);// v head-major row-major
  u16*   vtc_ = (u16*)  alloc(32ull * 32 * 4096 * 2);// v^T chunked [bh][ch][d][64]
  u16*   ao_  = (u16*)  alloc(4096ull * 1024 * 2);   // attention out bf16
  float* pO_  = (float*)alloc(32ull * 1024 * 2 * 64 * 4); // split partials O
  float* pML_ = (float*)alloc(32ull * 1024 * 2 * 2 * 4);  // split partials (m,l)

  cast_bf16_kernel<<<2048, 256, 0, stream>>>(x, xb, 4096 * 1024);
  transpose_cast_k<<<dim3(48, 16), 256, 0, stream>>>(Wqkv, wqt, 1024, 3072);
  transpose_cast_k<<<dim3(16, 16), 256, 0, stream>>>(Wo, wot, 1024, 1024);
  gemm_qkv<<<dim3(32 * 24), 256, 0, stream>>>(xb, wqt, bqkv, fc, fs, qr_, kr_, vr_);
  v_transpose_bf16<<<dim3(32, 32), 256, 0, stream>>>(vr_, vtc_);
  attn_k<<<dim3(768), 256, 0, stream>>>(qr_, kr_, vtc_, ao_, pO_, pML_);
  attn_merge<<<dim3(8192), 256, 0, stream>>>(pO_, pML_, ao_);
  gemm_bt<<<dim3(32 * 8), 256, 0, stream>>>(ao_, wot, bo, out, 4096, 1024, 1024);
}

// Round 15
// 128.945 us; speedup vs baseline: 1.0750x; 1.0750x over previous
//
#include <hip/hip_runtime.h>
#include <hip/hip_bf16.h>
#include <stdint.h>

typedef unsigned short u16;
typedef __attribute__((ext_vector_type(8))) __bf16 bf16x8;
typedef __attribute__((ext_vector_type(4))) float f32x4;
typedef __attribute__((ext_vector_type(16))) float f32x16;
typedef __attribute__((ext_vector_type(8))) u16 u16x8;

__device__ __forceinline__ u16 f2bf(float f) {
  union { float f; unsigned int u; } v; v.f = f;
  unsigned int r = v.u + 0x7fffu + ((v.u >> 16) & 1u);
  return (u16)(r >> 16);
}
__device__ __forceinline__ unsigned pack2(float lo, float hi) {
  return (unsigned)f2bf(lo) | ((unsigned)f2bf(hi) << 16);
}

__device__ __forceinline__ f32x4 mfma16(bf16x8 a, bf16x8 b, f32x4 c) {
  return __builtin_amdgcn_mfma_f32_16x16x32_bf16(a, b, c, 0, 0, 0);
}
__device__ __forceinline__ f32x16 mfma32(bf16x8 a, bf16x8 b, f32x16 c) {
  return __builtin_amdgcn_mfma_f32_32x32x16_bf16(a, b, c, 0, 0, 0);
}

__device__ __forceinline__ void gload16(const void* g, void* l) {
  __builtin_amdgcn_global_load_lds((const __attribute__((address_space(1))) void*)g,
                                   (__attribute__((address_space(3))) void*)l,
                                   16, 0, 0);
}

// ---------------- elementwise cast fp32 -> bf16 ----------------
__global__ void cast_bf16_kernel(const float* __restrict__ in, u16* __restrict__ out, int n) {
  int i = (blockIdx.x * 256 + threadIdx.x) * 8;
  if (i >= n) return;
  const float4* p = (const float4*)(in + i);
  float4 a = p[0], b = p[1];
  u16x8 o;
  o[0] = f2bf(a.x); o[1] = f2bf(a.y); o[2] = f2bf(a.z); o[3] = f2bf(a.w);
  o[4] = f2bf(b.x); o[5] = f2bf(b.y); o[6] = f2bf(b.z); o[7] = f2bf(b.w);
  *(u16x8*)(out + i) = o;
}

// ---------------- transpose + cast: in[R][C] fp32 -> out[C][R] bf16 ----------------
__global__ void transpose_cast_k(const float* __restrict__ in, u16* __restrict__ out,
                                 int R, int Ccols) {
  __shared__ float tile[64][65];
  const int c0 = (int)blockIdx.x << 6, r0 = (int)blockIdx.y << 6;
  const int tx = threadIdx.x & 63, ty = threadIdx.x >> 6;
#pragma unroll
  for (int i = ty; i < 64; i += 4)
    tile[i][tx] = in[(size_t)(r0 + i) * Ccols + c0 + tx];
  __syncthreads();
#pragma unroll
  for (int i = ty; i < 64; i += 4)
    out[(size_t)(c0 + i) * R + r0 + tx] = f2bf(tile[tx][i]);
}

// ---------------- QKV GEMM, BK=64, fused bias+RoPE+head-split epilogue ----------------
// V section now writes the chunked-transposed vtc[bh][ch][64 d][64 s] DIRECTLY:
// stage-1 writes the LDS tile transposed (smem[col][row]); stage-2 reads
// contiguous uint4 rows and stores 8KB-contiguous runs. Deletes the separate
// v_transpose kernel + 32MB of round-trip traffic.
__global__ __launch_bounds__(256, 3)
void gemm_qkv(const u16* __restrict__ A, const u16* __restrict__ Bt,
              const float* __restrict__ bias,
              const float* __restrict__ fc, const float* __restrict__ fs,
              u16* __restrict__ qr, u16* __restrict__ kr, u16* __restrict__ vtc) {
  const int K = 1024;
  __shared__ __align__(16) u16 smem[128 * 136];   // 34.8 KB; As/Bs alias front 32 KB
  u16* const As = smem;           // [2][128][32]
  u16* const Bs = smem + 8192;    // [2][128][32]
  const int m0 = (int)(blockIdx.x / 24) << 7;
  const int n0 = (int)(blockIdx.x % 24) << 7;
  const int tid = threadIdx.x;
  const int l = tid & 63, lg = l >> 4, ll = l & 15;
  const int w = tid >> 6;
  const int wr = (w >> 1) << 6, wc = (w & 1) << 6;
  const int srow = tid >> 2, scol = (tid & 3) << 3;
  const u16* ga = A + (size_t)(m0 + srow) * K + scol;
  const u16* gb = Bt + (size_t)(n0 + srow) * K + scol;
  const size_t K64 = (size_t)64 * K;
  u16* const la00 = &As[srow * 32 + scol];
  u16* const la01 = &As[4096 + srow * 32 + scol];
  u16* const la10 = &As[(srow + 64) * 32 + scol];
  u16* const la11 = &As[4096 + (srow + 64) * 32 + scol];
  u16* const lb00 = &Bs[srow * 32 + scol];
  u16* const lb01 = &Bs[4096 + srow * 32 + scol];
  u16* const lb10 = &Bs[(srow + 64) * 32 + scol];
  u16* const lb11 = &Bs[4096 + (srow + 64) * 32 + scol];
  f32x4 acc[4][4] = {};
  for (int kt = 0; kt < K; kt += 64) {
    gload16(ga + kt, la00);       gload16(ga + kt + 32, la01);
    gload16(ga + kt + K64, la10); gload16(ga + kt + K64 + 32, la11);
    gload16(gb + kt, lb00);       gload16(gb + kt + 32, lb01);
    gload16(gb + kt + K64, lb10); gload16(gb + kt + K64 + 32, lb11);
    __syncthreads();
#pragma unroll
    for (int h = 0; h < 2; ++h) {
      bf16x8 a[4], b[4];
#pragma unroll
      for (int i = 0; i < 4; ++i) {
        a[i] = *(const bf16x8*)&As[h * 4096 + (wr + i * 16 + ll) * 32 + lg * 8];
        b[i] = *(const bf16x8*)&Bs[h * 4096 + (wc + i * 16 + ll) * 32 + lg * 8];
      }
#pragma unroll
      for (int mi = 0; mi < 4; ++mi)
#pragma unroll
        for (int ni = 0; ni < 4; ++ni)
          acc[mi][ni] = mfma16(a[mi], b[ni], acc[mi][ni]);
    }
    __syncthreads();
  }
  // ---- stage 1: bias (+rope for Q/K) -> LDS tile ----
  // Q/K: smem[row][col] ([128][136]).  V: TRANSPOSED smem[col][row].
  const int sec = n0 >> 10;                       // 0=Q, 1=K, 2=V
  const int h0 = (n0 & 1023) >> 6;
#pragma unroll
  for (int ni = 0; ni < 4; ++ni) {
    const int cc = wc + ni * 16 + ll;
    const int n = n0 + cc;
    const int d = n & 63;
    const float bi_ = bias[n];
    const int i2 = d >> 1;
    const bool odd = d & 1;
#pragma unroll
    for (int mi = 0; mi < 4; ++mi) {
#pragma unroll
      for (int r = 0; r < 4; ++r) {
        const int rr = wr + mi * 16 + lg * 4 + r;
        const int s = (m0 + rr) & 2047;
        float v = acc[mi][ni][r] + bi_;
        if (sec < 2) {
          const float c = fc[s * 32 + i2], sn = fs[s * 32 + i2];
          const float p = __shfl_xor(v, 1);
          v = odd ? (p * sn + v * c) : (v * c - p * sn);
          if (sec == 0) v *= 0.125f;
          smem[rr * 136 + cc] = f2bf(v);
        } else {
          smem[cc * 136 + rr] = f2bf(v);        // transposed for vtc
        }
      }
    }
  }
  __syncthreads();
  // ---- stage 2: coalesced uint4 stores ----
  if (sec < 2) {
    u16* const dst = (sec == 0) ? qr : kr;
#pragma unroll
    for (int it = 0; it < 8; ++it) {
      const int c = it * 256 + tid;
      const int j = c & 7, hh = (c >> 3) & 1, rr = c >> 4;
      const int row = m0 + rr;
      const int bb = row >> 11, ss = row & 2047;
      const uint4 val = *(const uint4*)&smem[rr * 136 + hh * 64 + j * 8];
      *(uint4*)&dst[((size_t)(((bb << 4) + h0 + hh) << 11) + ss) * 64 + j * 8] = val;
    }
  } else {
    // V: vtc[((b*16 + h0+hh)*32 + chbase+chk)*4096 + d*64 + s_local]
    const int b16 = (m0 >> 11) << 4;
    const int chbase = (m0 & 2047) >> 6;
#pragma unroll
    for (int it = 0; it < 8; ++it) {
      const int c = it * 256 + tid;            // 2048 uint4 slots
      const int j2 = c & 7;                    // uint4 within 64-s row
      const int rr2 = c >> 3;                  // 0..255: chk*128 + hh*64 + d
      const int d = rr2 & 63, hh = (rr2 >> 6) & 1, chk = rr2 >> 7;
      const uint4 val = *(const uint4*)&smem[(hh * 64 + d) * 136 + chk * 64 + j2 * 8];
      *(uint4*)&vtc[(((size_t)(b16 + h0 + hh)) * 32 + chbase + chk) * 4096 + d * 64 + j2 * 8] = val;
    }
  }
}

// ---------------- GEMM (O-proj): BK=64, fp32 out ----------------
__global__ __launch_bounds__(256, 2)
void gemm_bt(const u16* __restrict__ A, const u16* __restrict__ Bt,
             const float* __restrict__ bias, float* __restrict__ C,
             int M, int N, int K) {
  __shared__ __align__(16) u16 As[2 * 128 * 32];
  __shared__ __align__(16) u16 Bs[2 * 128 * 32];
  const int nb = N >> 7;
  const int m0 = (int)(blockIdx.x / nb) << 7;
  const int n0 = (int)(blockIdx.x % nb) << 7;
  const int tid = threadIdx.x;
  const int l = tid & 63, lg = l >> 4, ll = l & 15;
  const int w = tid >> 6;
  const int wr = (w >> 1) << 6, wc = (w & 1) << 6;
  const int srow = tid >> 2, scol = (tid & 3) << 3;
  const u16* ga = A + (size_t)(m0 + srow) * K + scol;
  const u16* gb = Bt + (size_t)(n0 + srow) * K + scol;
  const size_t K64 = (size_t)64 * K;
  u16* const la00 = &As[srow * 32 + scol];
  u16* const la01 = &As[4096 + srow * 32 + scol];
  u16* const la10 = &As[(srow + 64) * 32 + scol];
  u16* const la11 = &As[4096 + (srow + 64) * 32 + scol];
  u16* const lb00 = &Bs[srow * 32 + scol];
  u16* const lb01 = &Bs[4096 + srow * 32 + scol];
  u16* const lb10 = &Bs[(srow + 64) * 32 + scol];
  u16* const lb11 = &Bs[4096 + (srow + 64) * 32 + scol];
  f32x4 acc[4][4] = {};
  for (int kt = 0; kt < K; kt += 64) {
    gload16(ga + kt, la00);       gload16(ga + kt + 32, la01);
    gload16(ga + kt + K64, la10); gload16(ga + kt + K64 + 32, la11);
    gload16(gb + kt, lb00);       gload16(gb + kt + 32, lb01);
    gload16(gb + kt + K64, lb10); gload16(gb + kt + K64 + 32, lb11);
    __syncthreads();
#pragma unroll
    for (int h = 0; h < 2; ++h) {
      bf16x8 a[4], b[4];
#pragma unroll
      for (int i = 0; i < 4; ++i) {
        a[i] = *(const bf16x8*)&As[h * 4096 + (wr + i * 16 + ll) * 32 + lg * 8];
        b[i] = *(const bf16x8*)&Bs[h * 4096 + (wc + i * 16 + ll) * 32 + lg * 8];
      }
#pragma unroll
      for (int mi = 0; mi < 4; ++mi)
#pragma unroll
        for (int ni = 0; ni < 4; ++ni)
          acc[mi][ni] = mfma16(a[mi], b[ni], acc[mi][ni]);
    }
    __syncthreads();
  }
#pragma unroll
  for (int mi = 0; mi < 4; ++mi) {
#pragma unroll
    for (int r = 0; r < 4; ++r) {
      const int row = m0 + wr + mi * 16 + lg * 4 + r;
      float* crow = C + (size_t)row * N + n0 + wc;
#pragma unroll
      for (int ni = 0; ni < 4; ++ni)
        crow[ni * 16 + ll] = acc[mi][ni][r] + bias[n0 + wc + ni * 16 + ll];
    }
  }
}

// ---------------- flash attention v5.1 (R11 verbatim, best known) ----------------
__global__ __launch_bounds__(256, 2)
void attn_k(const u16* __restrict__ qr, const u16* __restrict__ kr,
            const u16* __restrict__ vtc, u16* __restrict__ aout) {
  __shared__ __align__(16) char kvlds[16384];     // [0:8K) K tile, [8K:16K) V^T tile
  const int bi = (int)blockIdx.x;
  const int bh = bi & 31;
  const int qt = (bi < 256) ? (15 - (bi >> 5)) : ((bi - 256) >> 5);
  const int tid = threadIdx.x;
  const int w = tid >> 6, l = tid & 63, hi = l >> 5, ql = l & 31;
  const u16* Q  = qr + (size_t)bh * (2048 * 64);
  const u16* Kp = kr + (size_t)bh * (2048 * 64);
  const int q0w = (qt << 7) + (w << 5);
  const int qg = q0w + ql;
  bf16x8 qf[4];
#pragma unroll
  for (int mi = 0; mi < 4; ++mi)
    qf[mi] = *(const bf16x8*)&Q[(size_t)qg * 64 + mi * 16 + hi * 8];
  const int sr = tid >> 2, sc = (tid & 3) * 32;
  const int wo0 = (sr * 128 + sc) ^ ((sr & 7) << 4);
  const int wo1 = (sr * 128 + sc + 16) ^ ((sr & 7) << 4);
  const char* kga = (const char*)(Kp + (size_t)sr * 64) + sc;                    // + ch*8192
  const char* vga = (const char*)(vtc + (size_t)bh * 32 * 4096) + sr * 128 + sc; // + ch*8192
  const int swz = (ql & 7) << 4;
  f32x16 oa = {}, ob = {};
  float mrow = -1e30f, lp = 0.f;
  const int nch = 2 * qt + 2;
  uint4 sk0 = *(const uint4*)(kga), sk1 = *(const uint4*)(kga + 16);
  uint4 sv0 = *(const uint4*)(vga), sv1 = *(const uint4*)(vga + 16);
  for (int ch = 0; ch < nch; ++ch) {
    asm volatile("s_waitcnt vmcnt(0)" ::: "memory");
    asm volatile("s_barrier" ::: "memory");
    *(uint4*)(kvlds + wo0) = sk0;
    *(uint4*)(kvlds + wo1) = sk1;
    *(uint4*)(kvlds + 8192 + wo0) = sv0;
    *(uint4*)(kvlds + 8192 + wo1) = sv1;
    if (ch + 1 < nch) {
      const size_t kof = (size_t)(ch + 1) * 8192;
      sk0 = *(const uint4*)(kga + kof); sk1 = *(const uint4*)(kga + kof + 16);
      sv0 = *(const uint4*)(vga + kof); sv1 = *(const uint4*)(vga + kof + 16);
    }
    asm volatile("s_waitcnt lgkmcnt(0)" ::: "memory");
    asm volatile("s_barrier" ::: "memory");
    const int kb = ch << 6;
    if (kb > q0w + 31) continue;
    f32x16 s0 = {}, s1 = {};
#pragma unroll
    for (int mi = 0; mi < 4; ++mi) {
      const int cb = mi * 32 + hi * 16;
      const bf16x8 k0 = *(const bf16x8*)(kvlds + ((ql * 128 + cb) ^ swz));
      const bf16x8 k1 = *(const bf16x8*)(kvlds + (((32 + ql) * 128 + cb) ^ swz));
      s0 = mfma32(k0, qf[mi], s0);
      s1 = mfma32(k1, qf[mi], s1);
    }
    if (kb + 63 > q0w) {
#pragma unroll
      for (int r = 0; r < 16; ++r) {
        const int kvo = (r & 3) + 8 * (r >> 2) + 4 * hi;
        if (kb + kvo > qg) s0[r] = -1e30f;
        if (kb + 32 + kvo > qg) s1[r] = -1e30f;
      }
    }
    float mx = s0[0];
#pragma unroll
    for (int r = 1; r < 16; ++r) mx = fmaxf(mx, s0[r]);
#pragma unroll
    for (int r = 0; r < 16; ++r) mx = fmaxf(mx, s1[r]);
    mx = fmaxf(mx, __shfl_xor(mx, 32));
    if (!__all(mx <= mrow + 8.f)) {
      const float mn = fmaxf(mrow, mx);
      const float esc = __expf(mrow - mn);
      mrow = mn;
      lp *= esc;
#pragma unroll
      for (int r = 0; r < 16; ++r) { oa[r] *= esc; ob[r] *= esc; }
    }
    float p0[16], p1[16];
#pragma unroll
    for (int r = 0; r < 16; ++r) {
      p0[r] = __expf(s0[r] - mrow);
      p1[r] = __expf(s1[r] - mrow);
      lp += p0[r] + p1[r];
    }
    bf16x8 pb[4];
#pragma unroll
    for (int s = 0; s < 2; ++s) {
      const float* ps = s ? p1 : p0;
#pragma unroll
      for (int j = 0; j < 2; ++j) {
        const unsigned X0 = pack2(ps[j * 8 + 0], ps[j * 8 + 1]);
        const unsigned X1 = pack2(ps[j * 8 + 2], ps[j * 8 + 3]);
        const unsigned Y0 = pack2(ps[j * 8 + 4], ps[j * 8 + 5]);
        const unsigned Y1 = pack2(ps[j * 8 + 6], ps[j * 8 + 7]);
        const unsigned sX0 = (unsigned)__shfl_xor((int)X0, 32);
        const unsigned sX1 = (unsigned)__shfl_xor((int)X1, 32);
        const unsigned sY0 = (unsigned)__shfl_xor((int)Y0, 32);
        const unsigned sY1 = (unsigned)__shfl_xor((int)Y1, 32);
        union { unsigned u[4]; bf16x8 v; } t;
        t.u[0] = hi ? sY0 : X0;
        t.u[1] = hi ? sY1 : X1;
        t.u[2] = hi ? Y0 : sX0;
        t.u[3] = hi ? Y1 : sX1;
        pb[s * 2 + j] = t.v;
      }
    }
#pragma unroll
    for (int jj = 0; jj < 4; ++jj) {
      const int cb = jj * 32 + hi * 16;
      const bf16x8 va = *(const bf16x8*)(kvlds + 8192 + ((ql * 128 + cb) ^ swz));
      const bf16x8 vb = *(const bf16x8*)(kvlds + 8192 + (((32 + ql) * 128 + cb) ^ swz));
      oa = mfma32(va, pb[jj], oa);
      ob = mfma32(vb, pb[jj], ob);
    }
  }
  lp += __shfl_xor(lp, 32);
  const float inv = 1.0f / lp;
  const int hcol = (bh & 15) << 6;
  const int tok = ((bh >> 4) << 11) + qg;
  unsigned* orow = (unsigned*)(aout + (size_t)tok * 1024 + hcol);
#pragma unroll
  for (int r = 0; r < 16; r += 2) {
    const int d0 = (r & 3) + 8 * (r >> 2) + 4 * hi;
    orow[d0 >> 1]        = pack2(oa[r] * inv, oa[r + 1] * inv);
    orow[(32 + d0) >> 1] = pack2(ob[r] * inv, ob[r + 1] * inv);
  }
}

extern "C" void kernel_launch(void* const* d_in, const int* in_sizes, int n_in,
                              void* d_out, int out_size, void* d_ws, size_t ws_size,
                              hipStream_t stream) {
  const float* x    = (const float*)d_in[0];
  const float* fc   = (const float*)d_in[2];
  const float* fs   = (const float*)d_in[3];
  const float* Wqkv = (const float*)d_in[4];
  const float* bqkv = (const float*)d_in[5];
  const float* Wo   = (const float*)d_in[6];
  const float* bo   = (const float*)d_in[7];
  float* out = (float*)d_out;

  size_t off = 0;
  auto alloc = [&](size_t bytes) {
    void* p = (char*)d_ws + off;
    off += (bytes + 255) & ~(size_t)255;
    return p;
  };
  u16*   xb   = (u16*)  alloc(4096ull * 1024 * 2);   // x bf16
  u16*   wqt  = (u16*)  alloc(3072ull * 1024 * 2);   // W_qkv^T bf16
  u16*   wot  = (u16*)  alloc(1024ull * 1024 * 2);   // W_o^T bf16
  u16*   qr_  = (u16*)  alloc(32ull * 2048 * 64 * 2);// q roped, head-major
  u16*   kr_  = (u16*)  alloc(32ull * 2048 * 64 * 2);// k roped, head-major
  u16*   vtc_ = (u16*)  alloc(32ull * 32 * 4096 * 2);// v^T chunked [bh][ch][d][64]
  u16*   ao_  = (u16*)  alloc(4096ull * 1024 * 2);   // attention out bf16

  cast_bf16_kernel<<<2048, 256, 0, stream>>>(x, xb, 4096 * 1024);
  transpose_cast_k<<<dim3(48, 16), 256, 0, stream>>>(Wqkv, wqt, 1024, 3072);
  transpose_cast_k<<<dim3(16, 16), 256, 0, stream>>>(Wo, wot, 1024, 1024);
  gemm_qkv<<<dim3(32 * 24), 256, 0, stream>>>(xb, wqt, bqkv, fc, fs, qr_, kr_, vtc_);
  attn_k<<<dim3(512), 256, 0, stream>>>(qr_, kr_, vtc_, ao_);
  gemm_bt<<<dim3(32 * 8), 256, 0, stream>>>(ao_, wot, bo, out, 4096, 1024, 1024);
}